// Round 2
// baseline (3264.828 us; speedup 1.0000x reference)
//
#include <hip/hip_runtime.h>
#include <math.h>

#define FIN 256
#define HF  256   // H*FO
#define NH  8
#define TM  32    // nodes per GEMM block

// ---------------- GEMM: out[n, j] = dot(x[n,:], W[j,:]) (+bias) ----------------
// grid.y == 0: W = Wp   -> proj
// grid.y == 1: W = Wskip-> outskip (d_out), + bias
__global__ __launch_bounds__(256) void gemm_fused(
    const float* __restrict__ x, const float* __restrict__ Wp,
    const float* __restrict__ Wskip, const float* __restrict__ bias,
    float* __restrict__ proj, float* __restrict__ outskip, int N)
{
    __shared__ float xs[TM][FIN];
    const int tid  = threadIdx.x;
    const int base = blockIdx.x * TM;
    const float* __restrict__ W = (blockIdx.y == 0) ? Wp : Wskip;

    // stage x tile: TM*FIN = 8192 floats = 2048 float4, 8 per thread, coalesced
    #pragma unroll
    for (int i = 0; i < 8; ++i) {
        int idx = tid + i * 256;         // float4 index
        int m   = idx >> 6;              // 64 float4 per row
        int c   = (idx & 63) << 2;
        int row = base + m; if (row >= N) row = N - 1;
        *(float4*)&xs[m][c] = *(const float4*)&x[(size_t)row * FIN + c];
    }
    __syncthreads();

    const int cg = tid & 63;             // column group: 4 cols
    const int mg = tid >> 6;             // row group: 8 rows
    const int j  = cg << 2;

    float acc[8][4];
    #pragma unroll
    for (int m = 0; m < 8; ++m)
        #pragma unroll
        for (int q = 0; q < 4; ++q) acc[m][q] = 0.f;

    const float* w0p = W + (size_t)(j + 0) * FIN;
    const float* w1p = W + (size_t)(j + 1) * FIN;
    const float* w2p = W + (size_t)(j + 2) * FIN;
    const float* w3p = W + (size_t)(j + 3) * FIN;

    #pragma unroll 4
    for (int k0 = 0; k0 < FIN; k0 += 4) {
        float4 w0 = *(const float4*)(w0p + k0);
        float4 w1 = *(const float4*)(w1p + k0);
        float4 w2 = *(const float4*)(w2p + k0);
        float4 w3 = *(const float4*)(w3p + k0);
        #pragma unroll
        for (int m = 0; m < 8; ++m) {
            float4 xv = *(const float4*)&xs[mg * 8 + m][k0];
            acc[m][0] += xv.x * w0.x + xv.y * w0.y + xv.z * w0.z + xv.w * w0.w;
            acc[m][1] += xv.x * w1.x + xv.y * w1.y + xv.z * w1.z + xv.w * w1.w;
            acc[m][2] += xv.x * w2.x + xv.y * w2.y + xv.z * w2.z + xv.w * w2.w;
            acc[m][3] += xv.x * w3.x + xv.y * w3.y + xv.z * w3.z + xv.w * w3.w;
        }
    }

    float b0 = 0.f, b1 = 0.f, b2 = 0.f, b3 = 0.f;
    float* __restrict__ out = (blockIdx.y == 0) ? proj : outskip;
    if (blockIdx.y == 1) { b0 = bias[j]; b1 = bias[j+1]; b2 = bias[j+2]; b3 = bias[j+3]; }

    #pragma unroll
    for (int m = 0; m < 8; ++m) {
        int row = base + mg * 8 + m;
        if (row < N) {
            float4 v = make_float4(acc[m][0] + b0, acc[m][1] + b1,
                                   acc[m][2] + b2, acc[m][3] + b3);
            *(float4*)&out[(size_t)row * HF + j] = v;
        }
    }
}

// ---------------- scores: ssrc/strg[n,h] = sum_f proj[n,h,f]*a[h,f] ----------------
__global__ __launch_bounds__(256) void scores_k(
    const float* __restrict__ proj, const float* __restrict__ a_src,
    const float* __restrict__ a_trg, float* __restrict__ ssrc,
    float* __restrict__ strg, int N)
{
    const int lane = threadIdx.x & 63;
    const int node = blockIdx.x * 4 + (threadIdx.x >> 6);
    if (node >= N) return;
    float4 p  = *(const float4*)&proj[(size_t)node * HF + lane * 4];
    float4 as = *(const float4*)&a_src[lane * 4];
    float4 at = *(const float4*)&a_trg[lane * 4];
    float ps = p.x * as.x + p.y * as.y + p.z * as.z + p.w * as.w;
    float pt = p.x * at.x + p.y * at.y + p.z * at.z + p.w * at.w;
    #pragma unroll
    for (int off = 1; off < 8; off <<= 1) {
        ps += __shfl_xor(ps, off, 64);
        pt += __shfl_xor(pt, off, 64);
    }
    if ((lane & 7) == 0) {
        ssrc[node * NH + (lane >> 3)] = ps;
        strg[node * NH + (lane >> 3)] = pt;
    }
}

// ---------------- global max of leaky_relu(ssrc[src]+strg[trg]) ----------------
__device__ __forceinline__ float lrelu(float v) { return v > 0.f ? v : 0.2f * v; }

__global__ __launch_bounds__(256) void maxred_k(
    const int* __restrict__ ei, const float* __restrict__ ssrc,
    const float* __restrict__ strg, unsigned* __restrict__ gkey, int E)
{
    int gid = blockIdx.x * 256 + threadIdx.x;
    int stride = gridDim.x * 256;
    float lm = -3.4e38f;
    for (int e = gid; e < E; e += stride) {
        int s = ei[e];
        int t = ei[(size_t)E + e];
        const float4* a = (const float4*)&ssrc[(size_t)s * NH];
        const float4* b = (const float4*)&strg[(size_t)t * NH];
        float4 a0 = a[0], a1 = a[1], b0 = b[0], b1 = b[1];
        lm = fmaxf(lm, lrelu(a0.x + b0.x));
        lm = fmaxf(lm, lrelu(a0.y + b0.y));
        lm = fmaxf(lm, lrelu(a0.z + b0.z));
        lm = fmaxf(lm, lrelu(a0.w + b0.w));
        lm = fmaxf(lm, lrelu(a1.x + b1.x));
        lm = fmaxf(lm, lrelu(a1.y + b1.y));
        lm = fmaxf(lm, lrelu(a1.z + b1.z));
        lm = fmaxf(lm, lrelu(a1.w + b1.w));
    }
    #pragma unroll
    for (int off = 1; off < 64; off <<= 1) lm = fmaxf(lm, __shfl_xor(lm, off, 64));
    __shared__ float wmax[4];
    if ((threadIdx.x & 63) == 0) wmax[threadIdx.x >> 6] = lm;
    __syncthreads();
    if (threadIdx.x == 0) {
        float m = fmaxf(fmaxf(wmax[0], wmax[1]), fmaxf(wmax[2], wmax[3]));
        unsigned b = __float_as_uint(m);
        unsigned key = (b & 0x80000000u) ? ~b : (b | 0x80000000u);
        atomicMax(gkey, key);
    }
}

// ---------------- edge accumulate: one wave per edge ----------------
__global__ __launch_bounds__(256) void edge_k(
    const int* __restrict__ ei, const float* __restrict__ ssrc,
    const float* __restrict__ strg, const float* __restrict__ proj,
    const unsigned* __restrict__ gkey, float* __restrict__ acc,
    float* __restrict__ denom, int E)
{
    const int lane = threadIdx.x & 63;
    const int e = blockIdx.x * 4 + (threadIdx.x >> 6);
    if (e >= E) return;
    const int s = ei[e];
    const int t = ei[(size_t)E + e];

    unsigned key = *gkey;
    unsigned b = (key & 0x80000000u) ? (key ^ 0x80000000u) : ~key;
    const float gmax = __uint_as_float(b);

    const int h = lane >> 3;
    float sv = ssrc[(size_t)s * NH + h] + strg[(size_t)t * NH + h];
    sv = lrelu(sv);
    const float es = expf(sv - gmax);

    float4 p = *(const float4*)&proj[(size_t)s * HF + lane * 4];
    float* ap = &acc[(size_t)t * HF + lane * 4];
    atomicAdd(ap + 0, p.x * es);
    atomicAdd(ap + 1, p.y * es);
    atomicAdd(ap + 2, p.z * es);
    atomicAdd(ap + 3, p.w * es);
    if ((lane & 7) == 0) atomicAdd(&denom[(size_t)t * NH + h], es);
}

// ---------------- finalize: out = elu(acc/denom + skip) ----------------
__global__ __launch_bounds__(256) void final_k(
    const float* __restrict__ acc, const float* __restrict__ denom,
    float* __restrict__ out, int N)
{
    const int lane = threadIdx.x & 63;
    const int node = blockIdx.x * 4 + (threadIdx.x >> 6);
    if (node >= N) return;
    const int h = lane >> 3;
    const float d = denom[(size_t)node * NH + h] + 1e-16f;
    float4 a  = *(const float4*)&acc[(size_t)node * HF + lane * 4];
    float4 sk = *(const float4*)&out[(size_t)node * HF + lane * 4];
    float4 v;
    v.x = a.x / d + sk.x;
    v.y = a.y / d + sk.y;
    v.z = a.z / d + sk.z;
    v.w = a.w / d + sk.w;
    v.x = v.x > 0.f ? v.x : expm1f(v.x);
    v.y = v.y > 0.f ? v.y : expm1f(v.y);
    v.z = v.z > 0.f ? v.z : expm1f(v.z);
    v.w = v.w > 0.f ? v.w : expm1f(v.w);
    *(float4*)&out[(size_t)node * HF + lane * 4] = v;
}

extern "C" void kernel_launch(void* const* d_in, const int* in_sizes, int n_in,
                              void* d_out, int out_size, void* d_ws, size_t ws_size,
                              hipStream_t stream) {
    const float* x     = (const float*)d_in[0];
    const int*   ei    = (const int*)d_in[1];       // int32 on device (harness contract)
    const float* Wp    = (const float*)d_in[2];
    const float* a_src = (const float*)d_in[3];
    const float* a_trg = (const float*)d_in[4];
    const float* Wskip = (const float*)d_in[5];
    const float* bias  = (const float*)d_in[6];
    float* out = (float*)d_out;

    const int N = in_sizes[0] / FIN;
    const int E = in_sizes[1] / 2;

    float* proj  = (float*)d_ws;                    // N*256
    float* acc   = proj  + (size_t)N * HF;          // N*256
    float* denom = acc   + (size_t)N * HF;          // N*8
    float* ssrc  = denom + (size_t)N * NH;          // N*8
    float* strg  = ssrc  + (size_t)N * NH;          // N*8
    unsigned* gkey = (unsigned*)(strg + (size_t)N * NH); // 1

    // zero acc + denom (contiguous) and the max key
    hipMemsetAsync(acc, 0, ((size_t)N * HF + (size_t)N * NH) * sizeof(float), stream);
    hipMemsetAsync(gkey, 0, sizeof(unsigned), stream);

    dim3 ggrid((N + TM - 1) / TM, 2);
    gemm_fused<<<ggrid, 256, 0, stream>>>(x, Wp, Wskip, bias, proj, out, N);

    scores_k<<<(N + 3) / 4, 256, 0, stream>>>(proj, a_src, a_trg, ssrc, strg, N);

    maxred_k<<<1024, 256, 0, stream>>>(ei, ssrc, strg, gkey, E);

    edge_k<<<(E + 3) / 4, 256, 0, stream>>>(ei, ssrc, strg, proj, gkey, acc, denom, E);

    final_k<<<(N + 3) / 4, 256, 0, stream>>>(acc, denom, out, N);
}

// Round 3
// 724.224 us; speedup vs baseline: 4.5080x; 4.5080x over previous
//
#include <hip/hip_runtime.h>
#include <math.h>

#define FIN 256
#define HF  256   // H*FO
#define NH  8
#define TM  32    // nodes per GEMM block

// ---------------- GEMM: out[n, j] = dot(x[n,:], W[j,:]) (+bias) ----------------
__global__ __launch_bounds__(256) void gemm_fused(
    const float* __restrict__ x, const float* __restrict__ Wp,
    const float* __restrict__ Wskip, const float* __restrict__ bias,
    float* __restrict__ proj, float* __restrict__ outskip, int N)
{
    __shared__ float xs[TM][FIN];
    const int tid  = threadIdx.x;
    const int base = blockIdx.x * TM;
    const float* __restrict__ W = (blockIdx.y == 0) ? Wp : Wskip;

    #pragma unroll
    for (int i = 0; i < 8; ++i) {
        int idx = tid + i * 256;
        int m   = idx >> 6;
        int c   = (idx & 63) << 2;
        int row = base + m; if (row >= N) row = N - 1;
        *(float4*)&xs[m][c] = *(const float4*)&x[(size_t)row * FIN + c];
    }
    __syncthreads();

    const int cg = tid & 63;
    const int mg = tid >> 6;
    const int j  = cg << 2;

    float acc[8][4];
    #pragma unroll
    for (int m = 0; m < 8; ++m)
        #pragma unroll
        for (int q = 0; q < 4; ++q) acc[m][q] = 0.f;

    const float* w0p = W + (size_t)(j + 0) * FIN;
    const float* w1p = W + (size_t)(j + 1) * FIN;
    const float* w2p = W + (size_t)(j + 2) * FIN;
    const float* w3p = W + (size_t)(j + 3) * FIN;

    #pragma unroll 4
    for (int k0 = 0; k0 < FIN; k0 += 4) {
        float4 w0 = *(const float4*)(w0p + k0);
        float4 w1 = *(const float4*)(w1p + k0);
        float4 w2 = *(const float4*)(w2p + k0);
        float4 w3 = *(const float4*)(w3p + k0);
        #pragma unroll
        for (int m = 0; m < 8; ++m) {
            float4 xv = *(const float4*)&xs[mg * 8 + m][k0];
            acc[m][0] += xv.x * w0.x + xv.y * w0.y + xv.z * w0.z + xv.w * w0.w;
            acc[m][1] += xv.x * w1.x + xv.y * w1.y + xv.z * w1.z + xv.w * w1.w;
            acc[m][2] += xv.x * w2.x + xv.y * w2.y + xv.z * w2.z + xv.w * w2.w;
            acc[m][3] += xv.x * w3.x + xv.y * w3.y + xv.z * w3.z + xv.w * w3.w;
        }
    }

    float b0 = 0.f, b1 = 0.f, b2 = 0.f, b3 = 0.f;
    float* __restrict__ out = (blockIdx.y == 0) ? proj : outskip;
    if (blockIdx.y == 1) { b0 = bias[j]; b1 = bias[j+1]; b2 = bias[j+2]; b3 = bias[j+3]; }

    #pragma unroll
    for (int m = 0; m < 8; ++m) {
        int row = base + mg * 8 + m;
        if (row < N) {
            float4 v = make_float4(acc[m][0] + b0, acc[m][1] + b1,
                                   acc[m][2] + b2, acc[m][3] + b3);
            *(float4*)&out[(size_t)row * HF + j] = v;
        }
    }
}

// ---------------- scores ----------------
__global__ __launch_bounds__(256) void scores_k(
    const float* __restrict__ proj, const float* __restrict__ a_src,
    const float* __restrict__ a_trg, float* __restrict__ ssrc,
    float* __restrict__ strg, int N)
{
    const int lane = threadIdx.x & 63;
    const int node = blockIdx.x * 4 + (threadIdx.x >> 6);
    if (node >= N) return;
    float4 p  = *(const float4*)&proj[(size_t)node * HF + lane * 4];
    float4 as = *(const float4*)&a_src[lane * 4];
    float4 at = *(const float4*)&a_trg[lane * 4];
    float ps = p.x * as.x + p.y * as.y + p.z * as.z + p.w * as.w;
    float pt = p.x * at.x + p.y * at.y + p.z * at.z + p.w * at.w;
    #pragma unroll
    for (int off = 1; off < 8; off <<= 1) {
        ps += __shfl_xor(ps, off, 64);
        pt += __shfl_xor(pt, off, 64);
    }
    if ((lane & 7) == 0) {
        ssrc[node * NH + (lane >> 3)] = ps;
        strg[node * NH + (lane >> 3)] = pt;
    }
}

__device__ __forceinline__ float lrelu(float v) { return v > 0.f ? v : 0.2f * v; }

// ---------------- global max + degree histogram (fused edge pass) ----------------
__global__ __launch_bounds__(256) void maxhist_k(
    const int* __restrict__ ei, const float* __restrict__ ssrc,
    const float* __restrict__ strg, unsigned* __restrict__ gkey,
    int* __restrict__ deg, int E)
{
    int gid = blockIdx.x * 256 + threadIdx.x;
    int stride = gridDim.x * 256;
    float lm = -3.4e38f;
    for (int e = gid; e < E; e += stride) {
        int s = ei[e];
        int t = ei[(size_t)E + e];
        atomicAdd(&deg[t], 1);
        const float4* a = (const float4*)&ssrc[(size_t)s * NH];
        const float4* b = (const float4*)&strg[(size_t)t * NH];
        float4 a0 = a[0], a1 = a[1], b0 = b[0], b1 = b[1];
        lm = fmaxf(lm, lrelu(a0.x + b0.x));
        lm = fmaxf(lm, lrelu(a0.y + b0.y));
        lm = fmaxf(lm, lrelu(a0.z + b0.z));
        lm = fmaxf(lm, lrelu(a0.w + b0.w));
        lm = fmaxf(lm, lrelu(a1.x + b1.x));
        lm = fmaxf(lm, lrelu(a1.y + b1.y));
        lm = fmaxf(lm, lrelu(a1.z + b1.z));
        lm = fmaxf(lm, lrelu(a1.w + b1.w));
    }
    #pragma unroll
    for (int off = 1; off < 64; off <<= 1) lm = fmaxf(lm, __shfl_xor(lm, off, 64));
    __shared__ float wmax[4];
    if ((threadIdx.x & 63) == 0) wmax[threadIdx.x >> 6] = lm;
    __syncthreads();
    if (threadIdx.x == 0) {
        float m = fmaxf(fmaxf(wmax[0], wmax[1]), fmaxf(wmax[2], wmax[3]));
        unsigned b = __float_as_uint(m);
        unsigned key = (b & 0x80000000u) ? ~b : (b | 0x80000000u);
        atomicMax(gkey, key);
    }
}

// ---------------- exclusive prefix scan of deg -> rp (3 kernels) ----------------
// scan1: each block covers 4096 elements (16/thread), writes within-block
// exclusive prefix to rp and block total to bsum.
__global__ __launch_bounds__(256) void scan1_k(
    const int* __restrict__ deg, int* __restrict__ rp, int* __restrict__ bsum, int N)
{
    __shared__ int sh[256];
    const int tid = threadIdx.x;
    const int base = blockIdx.x * 4096 + tid * 16;
    int v[16], pre[16];
    int s = 0;
    #pragma unroll
    for (int i = 0; i < 16; ++i) {
        int idx = base + i;
        v[i] = (idx < N) ? deg[idx] : 0;
        pre[i] = s; s += v[i];
    }
    sh[tid] = s;
    __syncthreads();
    #pragma unroll
    for (int off = 1; off < 256; off <<= 1) {
        int t = (tid >= off) ? sh[tid - off] : 0;
        __syncthreads();
        sh[tid] += t;
        __syncthreads();
    }
    int texcl = sh[tid] - s;
    #pragma unroll
    for (int i = 0; i < 16; ++i) {
        int idx = base + i;
        if (idx < N) rp[idx] = texcl + pre[i];
    }
    if (tid == 255) bsum[blockIdx.x] = sh[255];
}

__global__ void scan2_k(int* bsum, int nsb) {
    if (threadIdx.x == 0 && blockIdx.x == 0) {
        int s = 0;
        for (int b = 0; b < nsb; ++b) { int v = bsum[b]; bsum[b] = s; s += v; }
    }
}

__global__ __launch_bounds__(256) void scan3_k(
    int* __restrict__ rp, const int* __restrict__ bsum,
    int* __restrict__ cursor, int N, int E)
{
    int gid = blockIdx.x * 256 + threadIdx.x;
    if (gid < N) {
        int v = rp[gid] + bsum[gid >> 12];
        rp[gid] = v;
        cursor[gid] = v;
    }
    if (gid == 0) rp[N] = E;
}

// ---------------- scatter: bucket src ids by target ----------------
__global__ __launch_bounds__(256) void scatter_k(
    const int* __restrict__ ei, int* __restrict__ cursor,
    int* __restrict__ col, int E)
{
    int gid = blockIdx.x * 256 + threadIdx.x;
    int stride = gridDim.x * 256;
    for (int e = gid; e < E; e += stride) {
        int s = ei[e];
        int t = ei[(size_t)E + e];
        int pos = atomicAdd(&cursor[t], 1);
        col[pos] = s;
    }
}

// ---------------- gather + finalize: one wave per target node ----------------
__global__ __launch_bounds__(256) void gather_k(
    const int* __restrict__ rp, const int* __restrict__ col,
    const float* __restrict__ ssrc, const float* __restrict__ strg,
    const float* __restrict__ proj, const unsigned* __restrict__ gkey,
    float* __restrict__ out, int N)
{
    const int lane = threadIdx.x & 63;
    const int node = blockIdx.x * 4 + (threadIdx.x >> 6);
    if (node >= N) return;
    const int h = lane >> 3;

    unsigned key = *gkey;
    unsigned b = (key & 0x80000000u) ? (key ^ 0x80000000u) : ~key;
    const float gmax = __uint_as_float(b);

    const float st = strg[(size_t)node * NH + h];
    const int beg = rp[node], end = rp[node + 1];

    float ax = 0.f, ay = 0.f, az = 0.f, aw = 0.f, den = 0.f;

    for (int i0 = beg; i0 < end; i0 += 64) {
        int ci = (i0 + lane < end) ? col[i0 + lane] : 0;
        int cnt = end - i0; if (cnt > 64) cnt = 64;
        for (int k = 0; k < cnt; ++k) {
            int s = __shfl(ci, k, 64);
            float sv = lrelu(ssrc[(size_t)s * NH + h] + st);
            float es = __expf(sv - gmax);
            float4 p = *(const float4*)&proj[(size_t)s * HF + lane * 4];
            ax += p.x * es; ay += p.y * es; az += p.z * es; aw += p.w * es;
            den += es;
        }
    }

    const float inv = 1.f / (den + 1e-16f);
    float4 sk = *(const float4*)&out[(size_t)node * HF + lane * 4];
    float4 v;
    v.x = ax * inv + sk.x;
    v.y = ay * inv + sk.y;
    v.z = az * inv + sk.z;
    v.w = aw * inv + sk.w;
    v.x = v.x > 0.f ? v.x : expm1f(v.x);
    v.y = v.y > 0.f ? v.y : expm1f(v.y);
    v.z = v.z > 0.f ? v.z : expm1f(v.z);
    v.w = v.w > 0.f ? v.w : expm1f(v.w);
    *(float4*)&out[(size_t)node * HF + lane * 4] = v;
}

extern "C" void kernel_launch(void* const* d_in, const int* in_sizes, int n_in,
                              void* d_out, int out_size, void* d_ws, size_t ws_size,
                              hipStream_t stream) {
    const float* x     = (const float*)d_in[0];
    const int*   ei    = (const int*)d_in[1];
    const float* Wp    = (const float*)d_in[2];
    const float* a_src = (const float*)d_in[3];
    const float* a_trg = (const float*)d_in[4];
    const float* Wskip = (const float*)d_in[5];
    const float* bias  = (const float*)d_in[6];
    float* out = (float*)d_out;

    const int N = in_sizes[0] / FIN;
    const int E = in_sizes[1] / 2;
    const int nsb = (N + 4095) / 4096;

    // workspace layout (floats first, 16B-aligned blocks)
    float* proj   = (float*)d_ws;                      // N*HF
    float* ssrc   = proj + (size_t)N * HF;             // N*NH
    float* strg   = ssrc + (size_t)N * NH;             // N*NH
    int*   deg    = (int*)(strg + (size_t)N * NH);     // N
    unsigned* gkey= (unsigned*)(deg + N);              // 1  (contiguous with deg for one memset)
    int*   rp     = (int*)(gkey + 1);                  // N+1
    int*   cursor = rp + (N + 1);                      // N
    int*   bsum   = cursor + N;                        // nsb (<=16)
    int*   col    = bsum + 16;                         // E

    // zero deg + gkey in one shot
    hipMemsetAsync(deg, 0, (size_t)(N + 1) * sizeof(int), stream);

    dim3 ggrid((N + TM - 1) / TM, 2);
    gemm_fused<<<ggrid, 256, 0, stream>>>(x, Wp, Wskip, bias, proj, out, N);

    scores_k<<<(N + 3) / 4, 256, 0, stream>>>(proj, a_src, a_trg, ssrc, strg, N);

    maxhist_k<<<1024, 256, 0, stream>>>(ei, ssrc, strg, gkey, deg, E);

    scan1_k<<<nsb, 256, 0, stream>>>(deg, rp, bsum, N);
    scan2_k<<<1, 64, 0, stream>>>(bsum, nsb);
    scan3_k<<<(N + 255) / 256, 256, 0, stream>>>(rp, bsum, cursor, N, E);

    scatter_k<<<1024, 256, 0, stream>>>(ei, cursor, col, E);

    gather_k<<<(N + 3) / 4, 256, 0, stream>>>(rp, col, ssrc, strg, proj, gkey, out, N);
}

// Round 4
// 423.003 us; speedup vs baseline: 7.7182x; 1.7121x over previous
//
#include <hip/hip_runtime.h>
#include <math.h>

#define FIN 256
#define HF  256   // H*FO
#define NH  8

typedef __bf16 bf16x8 __attribute__((ext_vector_type(8)));
typedef float  f32x4  __attribute__((ext_vector_type(4)));

__device__ __forceinline__ unsigned short f2bf(float f) {
    unsigned u = __float_as_uint(f);
    unsigned r = (u + 0x7fffu + ((u >> 16) & 1u)) >> 16;
    return (unsigned short)r;
}
__device__ __forceinline__ float bf2f(unsigned short h) {
    return __uint_as_float(((unsigned)h) << 16);
}

// ---------------- convert: split f32 -> bf16 hi|lo rows ----------------
// A2[M][512]: cols 0-255 hi, 256-511 lo.  W2[512][512]: rows 0-255 Wp, 256-511 Wskip.
__global__ __launch_bounds__(256) void convert_k(
    const float* __restrict__ x, const float* __restrict__ Wp,
    const float* __restrict__ Wskip, unsigned short* __restrict__ A2,
    unsigned short* __restrict__ W2, int M)
{
    const int l = threadIdx.x & 63;
    const int row = blockIdx.x * 4 + (threadIdx.x >> 6);
    const int total = M + 512;
    if (row >= total) return;
    const float* src;
    unsigned short* dst;
    if (row < M) { src = x + (size_t)row * 256; dst = A2 + (size_t)row * 512; }
    else {
        int j = row - M;
        src = (j < 256) ? Wp + (size_t)j * 256 : Wskip + (size_t)(j - 256) * 256;
        dst = W2 + (size_t)j * 512;
    }
    float4 v = *(const float4*)&src[l * 4];
    ushort4 h, lo;
    h.x = f2bf(v.x); lo.x = f2bf(v.x - bf2f(h.x));
    h.y = f2bf(v.y); lo.y = f2bf(v.y - bf2f(h.y));
    h.z = f2bf(v.z); lo.z = f2bf(v.z - bf2f(h.z));
    h.w = f2bf(v.w); lo.w = f2bf(v.w - bf2f(h.w));
    *(ushort4*)&dst[l * 4]       = h;
    *(ushort4*)&dst[256 + l * 4] = lo;
}

// ---------------- MFMA GEMM: C[M][512] = A x W^T ----------------
// cols 0-255 -> proj, cols 256-511 -> out (+bias)
__device__ __forceinline__ void gload16(const void* g, void* l) {
    __builtin_amdgcn_global_load_lds(
        (const __attribute__((address_space(1))) void*)g,
        (__attribute__((address_space(3))) void*)l, 16, 0, 0);
}

__global__ __launch_bounds__(256) void mfma_gemm(
    const unsigned short* __restrict__ A2, const unsigned short* __restrict__ W2,
    const float* __restrict__ bias, float* __restrict__ proj,
    float* __restrict__ out, int M)
{
    __shared__ __align__(16) unsigned short sAh[8192], sAl[8192], sBh[8192], sBl[8192];

    const int tid = threadIdx.x;
    const int l   = tid & 63;
    const int w   = tid >> 6;       // wave 0..3
    const int wr  = w >> 1, wc = w & 1;
    const int brow = blockIdx.x * 128;
    const int bcol = blockIdx.y * 128;

    f32x4 acc[4][4];
    #pragma unroll
    for (int a = 0; a < 4; ++a)
        #pragma unroll
        for (int b = 0; b < 4; ++b) acc[a][b] = (f32x4){0.f, 0.f, 0.f, 0.f};

    // staging lane constants: each wave-instr stages 8 rows x 128B (swizzled source)
    const int srow = l >> 3;              // row within 8-row group
    const int sseg = (l & 7) ^ srow;      // inverse-swizzled source 16B-segment

    for (int kk = 0; kk < 4; ++kk) {
        #pragma unroll
        for (int i = 0; i < 4; ++i) {
            const int rl  = w * 32 + i * 8 + srow;     // local row 0..127
            const int lds = (w * 32 + i * 8) * 64;     // ushort index (row start)
            int ga = brow + rl; if (ga >= M) ga = M - 1;
            const unsigned short* gA = A2 + (size_t)ga * 512 + kk * 64 + sseg * 8;
            const unsigned short* gB = W2 + (size_t)(bcol + rl) * 512 + kk * 64 + sseg * 8;
            gload16(gA,       &sAh[lds]);
            gload16(gA + 256, &sAl[lds]);
            gload16(gB,       &sBh[lds]);
            gload16(gB + 256, &sBl[lds]);
        }
        __syncthreads();

        #pragma unroll
        for (int ks = 0; ks < 2; ++ks) {
            const int sg = ((ks * 4) + (l >> 4)) ^ (l & 7);   // swizzled read segment
            bf16x8 ah[4], al[4], bh[4], bl[4];
            #pragma unroll
            for (int f = 0; f < 4; ++f) {
                const int ra = wr * 64 + f * 16 + (l & 15);
                const int rb = wc * 64 + f * 16 + (l & 15);
                ah[f] = *(const bf16x8*)&sAh[ra * 64 + sg * 8];
                al[f] = *(const bf16x8*)&sAl[ra * 64 + sg * 8];
                bh[f] = *(const bf16x8*)&sBh[rb * 64 + sg * 8];
                bl[f] = *(const bf16x8*)&sBl[rb * 64 + sg * 8];
            }
            #pragma unroll
            for (int fm = 0; fm < 4; ++fm)
                #pragma unroll
                for (int fn = 0; fn < 4; ++fn) {
                    acc[fm][fn] = __builtin_amdgcn_mfma_f32_16x16x32_bf16(ah[fm], bh[fn], acc[fm][fn], 0, 0, 0);
                    acc[fm][fn] = __builtin_amdgcn_mfma_f32_16x16x32_bf16(ah[fm], bl[fn], acc[fm][fn], 0, 0, 0);
                    acc[fm][fn] = __builtin_amdgcn_mfma_f32_16x16x32_bf16(al[fm], bh[fn], acc[fm][fn], 0, 0, 0);
                }
        }
        __syncthreads();
    }

    // epilogue: C/D layout col=lane&15, row=(lane>>4)*4+q
    const bool isProj = (bcol < 256);
    #pragma unroll
    for (int fn = 0; fn < 4; ++fn) {
        const int col = bcol + wc * 64 + fn * 16 + (l & 15);
        const float bv = isProj ? 0.f : bias[col - 256];
        float* dst = isProj ? (proj + col) : (out + (col - 256));
        #pragma unroll
        for (int fm = 0; fm < 4; ++fm) {
            const int r0 = brow + wr * 64 + fm * 16 + (l >> 4) * 4;
            #pragma unroll
            for (int q = 0; q < 4; ++q) {
                const int row = r0 + q;
                if (row < M) dst[(size_t)row * 256] = acc[fm][fn][q] + bv;
            }
        }
    }
}

// ---------------- scores ----------------
__global__ __launch_bounds__(256) void scores_k(
    const float* __restrict__ proj, const float* __restrict__ a_src,
    const float* __restrict__ a_trg, float* __restrict__ ssrc,
    float* __restrict__ strg, int N)
{
    const int lane = threadIdx.x & 63;
    const int node = blockIdx.x * 4 + (threadIdx.x >> 6);
    if (node >= N) return;
    float4 p  = *(const float4*)&proj[(size_t)node * HF + lane * 4];
    float4 as = *(const float4*)&a_src[lane * 4];
    float4 at = *(const float4*)&a_trg[lane * 4];
    float ps = p.x * as.x + p.y * as.y + p.z * as.z + p.w * as.w;
    float pt = p.x * at.x + p.y * at.y + p.z * at.z + p.w * at.w;
    #pragma unroll
    for (int off = 1; off < 8; off <<= 1) {
        ps += __shfl_xor(ps, off, 64);
        pt += __shfl_xor(pt, off, 64);
    }
    if ((lane & 7) == 0) {
        ssrc[node * NH + (lane >> 3)] = ps;
        strg[node * NH + (lane >> 3)] = pt;
    }
}

__device__ __forceinline__ float lrelu(float v) { return v > 0.f ? v : 0.2f * v; }

// ---------------- degree histogram ----------------
__global__ __launch_bounds__(256) void hist_k(
    const int* __restrict__ ei, int* __restrict__ deg, int E)
{
    int gid = blockIdx.x * 256 + threadIdx.x;
    int stride = gridDim.x * 256;
    for (int e = gid; e < E; e += stride)
        atomicAdd(&deg[ei[(size_t)E + e]], 1);
}

// ---------------- exclusive prefix scan of deg -> rp ----------------
__global__ __launch_bounds__(256) void scan1_k(
    const int* __restrict__ deg, int* __restrict__ rp, int* __restrict__ bsum, int N)
{
    __shared__ int sh[256];
    const int tid = threadIdx.x;
    const int base = blockIdx.x * 4096 + tid * 16;
    int v[16], pre[16];
    int s = 0;
    #pragma unroll
    for (int i = 0; i < 16; ++i) {
        int idx = base + i;
        v[i] = (idx < N) ? deg[idx] : 0;
        pre[i] = s; s += v[i];
    }
    sh[tid] = s;
    __syncthreads();
    #pragma unroll
    for (int off = 1; off < 256; off <<= 1) {
        int t = (tid >= off) ? sh[tid - off] : 0;
        __syncthreads();
        sh[tid] += t;
        __syncthreads();
    }
    int texcl = sh[tid] - s;
    #pragma unroll
    for (int i = 0; i < 16; ++i) {
        int idx = base + i;
        if (idx < N) rp[idx] = texcl + pre[i];
    }
    if (tid == 255) bsum[blockIdx.x] = sh[255];
}

__global__ void scan2_k(int* bsum, int nsb) {
    if (threadIdx.x == 0 && blockIdx.x == 0) {
        int s = 0;
        for (int b = 0; b < nsb; ++b) { int v = bsum[b]; bsum[b] = s; s += v; }
    }
}

__global__ __launch_bounds__(256) void scan3_k(
    int* __restrict__ rp, const int* __restrict__ bsum,
    int* __restrict__ cursor, int N, int E)
{
    int gid = blockIdx.x * 256 + threadIdx.x;
    if (gid < N) {
        int v = rp[gid] + bsum[gid >> 12];
        rp[gid] = v;
        cursor[gid] = v;
    }
    if (gid == 0) rp[N] = E;
}

// ---------------- scatter: bucket src ids by target ----------------
__global__ __launch_bounds__(256) void scatter_k(
    const int* __restrict__ ei, int* __restrict__ cursor,
    int* __restrict__ col, int E)
{
    int gid = blockIdx.x * 256 + threadIdx.x;
    int stride = gridDim.x * 256;
    for (int e = gid; e < E; e += stride) {
        int s = ei[e];
        int t = ei[(size_t)E + e];
        int pos = atomicAdd(&cursor[t], 1);
        col[pos] = s;
    }
}

// ---------------- gather + finalize: one wave per target node ----------------
__global__ __launch_bounds__(256) void gather_k(
    const int* __restrict__ rp, const int* __restrict__ col,
    const float* __restrict__ ssrc, const float* __restrict__ strg,
    const float* __restrict__ proj, float* __restrict__ out, int N)
{
    const int lane = threadIdx.x & 63;
    const int node = blockIdx.x * 4 + (threadIdx.x >> 6);
    if (node >= N) return;
    const int h = lane >> 3;

    const float st = strg[(size_t)node * NH + h];
    const int beg = rp[node], end = rp[node + 1];

    float ax = 0.f, ay = 0.f, az = 0.f, aw = 0.f, den = 0.f;

    for (int i0 = beg; i0 < end; i0 += 64) {
        int ci = (i0 + lane < end) ? col[i0 + lane] : 0;
        int cnt = end - i0; if (cnt > 64) cnt = 64;
        for (int k = 0; k < cnt; ++k) {
            int s = __shfl(ci, k, 64);
            float sv = lrelu(ssrc[(size_t)s * NH + h] + st);
            float es = __expf(sv);
            float4 p = *(const float4*)&proj[(size_t)s * HF + lane * 4];
            ax += p.x * es; ay += p.y * es; az += p.z * es; aw += p.w * es;
            den += es;
        }
    }

    const float inv = 1.f / (den + 1e-16f);
    float4 sk = *(const float4*)&out[(size_t)node * HF + lane * 4];
    float4 v;
    v.x = ax * inv + sk.x;
    v.y = ay * inv + sk.y;
    v.z = az * inv + sk.z;
    v.w = aw * inv + sk.w;
    v.x = v.x > 0.f ? v.x : expm1f(v.x);
    v.y = v.y > 0.f ? v.y : expm1f(v.y);
    v.z = v.z > 0.f ? v.z : expm1f(v.z);
    v.w = v.w > 0.f ? v.w : expm1f(v.w);
    *(float4*)&out[(size_t)node * HF + lane * 4] = v;
}

extern "C" void kernel_launch(void* const* d_in, const int* in_sizes, int n_in,
                              void* d_out, int out_size, void* d_ws, size_t ws_size,
                              hipStream_t stream) {
    const float* x     = (const float*)d_in[0];
    const int*   ei    = (const int*)d_in[1];
    const float* Wp    = (const float*)d_in[2];
    const float* a_src = (const float*)d_in[3];
    const float* a_trg = (const float*)d_in[4];
    const float* Wskip = (const float*)d_in[5];
    const float* bias  = (const float*)d_in[6];
    float* out = (float*)d_out;

    const int N = in_sizes[0] / FIN;
    const int E = in_sizes[1] / 2;
    const int nsb = (N + 4095) / 4096;

    // workspace layout
    float* proj          = (float*)d_ws;                         // N*HF
    float* ssrc          = proj + (size_t)N * HF;                // N*NH
    float* strg          = ssrc + (size_t)N * NH;                // N*NH
    unsigned short* A2   = (unsigned short*)(strg + (size_t)N * NH);  // N*512
    unsigned short* W2   = A2 + (size_t)N * 512;                 // 512*512
    int* deg             = (int*)(W2 + 512 * 512);               // N
    int* rp              = deg + N;                              // N+1
    int* cursor          = rp + (N + 1);                         // N
    int* bsum            = cursor + N;                           // 16
    int* col             = bsum + 16;                            // E

    hipMemsetAsync(deg, 0, (size_t)N * sizeof(int), stream);

    convert_k<<<(N + 512 + 3) / 4, 256, 0, stream>>>(x, Wp, Wskip, A2, W2, N);

    dim3 ggrid((N + 127) / 128, 4);
    mfma_gemm<<<ggrid, 256, 0, stream>>>(A2, W2, bias, proj, out, N);

    scores_k<<<(N + 3) / 4, 256, 0, stream>>>(proj, a_src, a_trg, ssrc, strg, N);

    hist_k<<<1024, 256, 0, stream>>>(ei, deg, E);

    scan1_k<<<nsb, 256, 0, stream>>>(deg, rp, bsum, N);
    scan2_k<<<1, 64, 0, stream>>>(bsum, nsb);
    scan3_k<<<(N + 255) / 256, 256, 0, stream>>>(rp, bsum, cursor, N, E);

    scatter_k<<<1024, 256, 0, stream>>>(ei, cursor, col, E);

    gather_k<<<(N + 3) / 4, 256, 0, stream>>>(rp, col, ssrc, strg, proj, out, N);
}

// Round 6
// 367.579 us; speedup vs baseline: 8.8820x; 1.1508x over previous
//
#include <hip/hip_runtime.h>
#include <math.h>

#define FIN 256
#define HF  256   // H*FO
#define NH  8

typedef __bf16 bf16x8 __attribute__((ext_vector_type(8)));
typedef float  f32x4  __attribute__((ext_vector_type(4)));

__device__ __forceinline__ unsigned short f2bf(float f) {
    unsigned u = __float_as_uint(f);
    unsigned r = (u + 0x7fffu + ((u >> 16) & 1u)) >> 16;
    return (unsigned short)r;
}
__device__ __forceinline__ float bf2f(unsigned short h) {
    return __uint_as_float(((unsigned)h) << 16);
}

// ---------------- convert: split f32 -> bf16 hi|lo rows ----------------
// A2[M][512]: cols 0-255 hi, 256-511 lo.  W2[512][512]: rows 0-255 Wp, 256-511 Wskip.
__global__ __launch_bounds__(256) void convert_k(
    const float* __restrict__ x, const float* __restrict__ Wp,
    const float* __restrict__ Wskip, unsigned short* __restrict__ A2,
    unsigned short* __restrict__ W2, int M)
{
    const int l = threadIdx.x & 63;
    const int row = blockIdx.x * 4 + (threadIdx.x >> 6);
    const int total = M + 512;
    if (row >= total) return;
    const float* src;
    unsigned short* dst;
    if (row < M) { src = x + (size_t)row * 256; dst = A2 + (size_t)row * 512; }
    else {
        int j = row - M;
        src = (j < 256) ? Wp + (size_t)j * 256 : Wskip + (size_t)(j - 256) * 256;
        dst = W2 + (size_t)j * 512;
    }
    float4 v = *(const float4*)&src[l * 4];
    ushort4 h, lo;
    h.x = f2bf(v.x); lo.x = f2bf(v.x - bf2f(h.x));
    h.y = f2bf(v.y); lo.y = f2bf(v.y - bf2f(h.y));
    h.z = f2bf(v.z); lo.z = f2bf(v.z - bf2f(h.z));
    h.w = f2bf(v.w); lo.w = f2bf(v.w - bf2f(h.w));
    *(ushort4*)&dst[l * 4]       = h;
    *(ushort4*)&dst[256 + l * 4] = lo;
}

// ---------------- MFMA GEMM: C[M][512] = A x W^T ----------------
// cols 0-255: write projb (bf16) + fused scores (f32, exact from acc)
// cols 256-511: write out (f32) + bias
__device__ __forceinline__ void gload16(const void* g, void* l) {
    __builtin_amdgcn_global_load_lds(
        (const __attribute__((address_space(1))) void*)g,
        (__attribute__((address_space(3))) void*)l, 16, 0, 0);
}

__global__ __launch_bounds__(256) void mfma_gemm(
    const unsigned short* __restrict__ A2, const unsigned short* __restrict__ W2,
    const float* __restrict__ bias, const float* __restrict__ a_src,
    const float* __restrict__ a_trg, unsigned short* __restrict__ projb,
    float* __restrict__ ssrc, float* __restrict__ strg,
    float* __restrict__ out, int M)
{
    __shared__ __align__(16) unsigned short sAh[8192], sAl[8192], sBh[8192], sBl[8192];

    const int tid = threadIdx.x;
    const int l   = tid & 63;
    const int w   = tid >> 6;       // wave 0..3
    const int wr  = w >> 1, wc = w & 1;
    const int brow = blockIdx.x * 128;
    const int bcol = blockIdx.y * 128;

    f32x4 acc[4][4];
    #pragma unroll
    for (int a = 0; a < 4; ++a)
        #pragma unroll
        for (int b = 0; b < 4; ++b) acc[a][b] = (f32x4){0.f, 0.f, 0.f, 0.f};

    const int srow = l >> 3;              // row within 8-row group
    const int sseg = (l & 7) ^ srow;      // inverse-swizzled source 16B-segment

    for (int kk = 0; kk < 4; ++kk) {
        #pragma unroll
        for (int i = 0; i < 4; ++i) {
            const int rl  = w * 32 + i * 8 + srow;     // local row 0..127
            const int lds = (w * 32 + i * 8) * 64;     // ushort index (row start)
            int ga = brow + rl; if (ga >= M) ga = M - 1;
            const unsigned short* gA = A2 + (size_t)ga * 512 + kk * 64 + sseg * 8;
            const unsigned short* gB = W2 + (size_t)(bcol + rl) * 512 + kk * 64 + sseg * 8;
            gload16(gA,       &sAh[lds]);
            gload16(gA + 256, &sAl[lds]);
            gload16(gB,       &sBh[lds]);
            gload16(gB + 256, &sBl[lds]);
        }
        __syncthreads();

        #pragma unroll
        for (int ks = 0; ks < 2; ++ks) {
            const int sg = ((ks * 4) + (l >> 4)) ^ (l & 7);   // swizzled read segment
            bf16x8 ah[4], al[4], bh[4], bl[4];
            #pragma unroll
            for (int f = 0; f < 4; ++f) {
                const int ra = wr * 64 + f * 16 + (l & 15);
                const int rb = wc * 64 + f * 16 + (l & 15);
                ah[f] = *(const bf16x8*)&sAh[ra * 64 + sg * 8];
                al[f] = *(const bf16x8*)&sAl[ra * 64 + sg * 8];
                bh[f] = *(const bf16x8*)&sBh[rb * 64 + sg * 8];
                bl[f] = *(const bf16x8*)&sBl[rb * 64 + sg * 8];
            }
            #pragma unroll
            for (int fm = 0; fm < 4; ++fm)
                #pragma unroll
                for (int fn = 0; fn < 4; ++fn) {
                    acc[fm][fn] = __builtin_amdgcn_mfma_f32_16x16x32_bf16(ah[fm], bh[fn], acc[fm][fn], 0, 0, 0);
                    acc[fm][fn] = __builtin_amdgcn_mfma_f32_16x16x32_bf16(ah[fm], bl[fn], acc[fm][fn], 0, 0, 0);
                    acc[fm][fn] = __builtin_amdgcn_mfma_f32_16x16x32_bf16(al[fm], bh[fn], acc[fm][fn], 0, 0, 0);
                }
        }
        __syncthreads();
    }

    // epilogue: C/D layout col=lane&15, row=(lane>>4)*4+q
    if (bcol < 256) {
        // ---- proj block: write bf16 projb + fused exact-f32 scores ----
        float as[4], at[4];
        #pragma unroll
        for (int fn = 0; fn < 4; ++fn) {
            const int col = bcol + wc * 64 + fn * 16 + (l & 15);
            as[fn] = a_src[col];
            at[fn] = a_trg[col];
        }
        #pragma unroll
        for (int fn = 0; fn < 4; ++fn) {
            const int col = bcol + wc * 64 + fn * 16 + (l & 15);
            #pragma unroll
            for (int fm = 0; fm < 4; ++fm) {
                const int r0 = brow + wr * 64 + fm * 16 + (l >> 4) * 4;
                #pragma unroll
                for (int q = 0; q < 4; ++q) {
                    const int row = r0 + q;
                    if (row < M) projb[(size_t)row * 256 + col] = f2bf(acc[fm][fn][q]);
                }
            }
        }
        const int headA = ((bcol + wc * 64) >> 5);
        const int headB = headA + 1;
        #pragma unroll
        for (int fm = 0; fm < 4; ++fm) {
            #pragma unroll
            for (int q = 0; q < 4; ++q) {
                float p0 = acc[fm][0][q] * as[0] + acc[fm][1][q] * as[1];
                float p1 = acc[fm][2][q] * as[2] + acc[fm][3][q] * as[3];
                float t0 = acc[fm][0][q] * at[0] + acc[fm][1][q] * at[1];
                float t1 = acc[fm][2][q] * at[2] + acc[fm][3][q] * at[3];
                #pragma unroll
                for (int m = 1; m < 16; m <<= 1) {
                    p0 += __shfl_xor(p0, m, 64);
                    p1 += __shfl_xor(p1, m, 64);
                    t0 += __shfl_xor(t0, m, 64);
                    t1 += __shfl_xor(t1, m, 64);
                }
                if ((l & 15) == 0) {
                    const int row = brow + wr * 64 + fm * 16 + (l >> 4) * 4 + q;
                    if (row < M) {
                        ssrc[(size_t)row * NH + headA] = p0;
                        ssrc[(size_t)row * NH + headB] = p1;
                        strg[(size_t)row * NH + headA] = t0;
                        strg[(size_t)row * NH + headB] = t1;
                    }
                }
            }
        }
    } else {
        // ---- skip block: out = acc + bias ----
        #pragma unroll
        for (int fn = 0; fn < 4; ++fn) {
            const int col = bcol + wc * 64 + fn * 16 + (l & 15);
            const float bv = bias[col - 256];
            float* dst = out + (col - 256);
            #pragma unroll
            for (int fm = 0; fm < 4; ++fm) {
                const int r0 = brow + wr * 64 + fm * 16 + (l >> 4) * 4;
                #pragma unroll
                for (int q = 0; q < 4; ++q) {
                    const int row = r0 + q;
                    if (row < M) dst[(size_t)row * 256] = acc[fm][fn][q] + bv;
                }
            }
        }
    }
}

__device__ __forceinline__ float lrelu(float v) { return v > 0.f ? v : 0.2f * v; }

// ---------------- degree histogram ----------------
__global__ __launch_bounds__(256) void hist_k(
    const int* __restrict__ ei, int* __restrict__ deg, int E)
{
    int gid = blockIdx.x * 256 + threadIdx.x;
    int stride = gridDim.x * 256;
    for (int e = gid; e < E; e += stride)
        atomicAdd(&deg[ei[(size_t)E + e]], 1);
}

// ---------------- exclusive prefix scan of deg -> rp ----------------
__global__ __launch_bounds__(256) void scan1_k(
    const int* __restrict__ deg, int* __restrict__ rp, int* __restrict__ bsum, int N)
{
    __shared__ int sh[256];
    const int tid = threadIdx.x;
    const int base = blockIdx.x * 4096 + tid * 16;
    int v[16], pre[16];
    int s = 0;
    #pragma unroll
    for (int i = 0; i < 16; ++i) {
        int idx = base + i;
        v[i] = (idx < N) ? deg[idx] : 0;
        pre[i] = s; s += v[i];
    }
    sh[tid] = s;
    __syncthreads();
    #pragma unroll
    for (int off = 1; off < 256; off <<= 1) {
        int t = (tid >= off) ? sh[tid - off] : 0;
        __syncthreads();
        sh[tid] += t;
        __syncthreads();
    }
    int texcl = sh[tid] - s;
    #pragma unroll
    for (int i = 0; i < 16; ++i) {
        int idx = base + i;
        if (idx < N) rp[idx] = texcl + pre[i];
    }
    if (tid == 255) bsum[blockIdx.x] = sh[255];
}

__global__ void scan2_k(int* bsum, int nsb) {
    if (threadIdx.x == 0 && blockIdx.x == 0) {
        int s = 0;
        for (int b = 0; b < nsb; ++b) { int v = bsum[b]; bsum[b] = s; s += v; }
    }
}

__global__ __launch_bounds__(256) void scan3_k(
    int* __restrict__ rp, const int* __restrict__ bsum,
    int* __restrict__ cursor, int N, int E)
{
    int gid = blockIdx.x * 256 + threadIdx.x;
    if (gid < N) {
        int v = rp[gid] + bsum[gid >> 12];
        rp[gid] = v;
        cursor[gid] = v;
    }
    if (gid == 0) rp[N] = E;
}

// ---------------- scatter: bucket src ids by target ----------------
__global__ __launch_bounds__(256) void scatter_k(
    const int* __restrict__ ei, int* __restrict__ cursor,
    int* __restrict__ col, int E)
{
    int gid = blockIdx.x * 256 + threadIdx.x;
    int stride = gridDim.x * 256;
    for (int e = gid; e < E; e += stride) {
        int s = ei[e];
        int t = ei[(size_t)E + e];
        int pos = atomicAdd(&cursor[t], 1);
        col[pos] = s;
    }
}

// ---------------- gather + finalize: one wave per target node (bf16 proj) ----------------
__global__ __launch_bounds__(256) void gather_k(
    const int* __restrict__ rp, const int* __restrict__ col,
    const float* __restrict__ ssrc, const float* __restrict__ strg,
    const unsigned short* __restrict__ projb, float* __restrict__ out, int N)
{
    const int lane = threadIdx.x & 63;
    const int node = blockIdx.x * 4 + (threadIdx.x >> 6);
    if (node >= N) return;
    const int h = lane >> 3;

    const float st = strg[(size_t)node * NH + h];
    const int beg = rp[node], end = rp[node + 1];

    float ax = 0.f, ay = 0.f, az = 0.f, aw = 0.f, den = 0.f;

    for (int i0 = beg; i0 < end; i0 += 64) {
        int ci = (i0 + lane < end) ? col[i0 + lane] : 0;
        int cnt = end - i0; if (cnt > 64) cnt = 64;
        int k = 0;
        for (; k + 1 < cnt; k += 2) {
            int s0 = __shfl(ci, k, 64);
            int s1 = __shfl(ci, k + 1, 64);
            ushort4 r0 = *(const ushort4*)&projb[(size_t)s0 * HF + lane * 4];
            ushort4 r1 = *(const ushort4*)&projb[(size_t)s1 * HF + lane * 4];
            float e0 = __expf(lrelu(ssrc[(size_t)s0 * NH + h] + st));
            float e1 = __expf(lrelu(ssrc[(size_t)s1 * NH + h] + st));
            ax += bf2f(r0.x) * e0 + bf2f(r1.x) * e1;
            ay += bf2f(r0.y) * e0 + bf2f(r1.y) * e1;
            az += bf2f(r0.z) * e0 + bf2f(r1.z) * e1;
            aw += bf2f(r0.w) * e0 + bf2f(r1.w) * e1;
            den += e0 + e1;
        }
        if (k < cnt) {
            int s0 = __shfl(ci, k, 64);
            ushort4 r0 = *(const ushort4*)&projb[(size_t)s0 * HF + lane * 4];
            float e0 = __expf(lrelu(ssrc[(size_t)s0 * NH + h] + st));
            ax += bf2f(r0.x) * e0;
            ay += bf2f(r0.y) * e0;
            az += bf2f(r0.z) * e0;
            aw += bf2f(r0.w) * e0;
            den += e0;
        }
    }

    const float inv = 1.f / (den + 1e-16f);
    float4 sk = *(const float4*)&out[(size_t)node * HF + lane * 4];
    float4 v;
    v.x = ax * inv + sk.x;
    v.y = ay * inv + sk.y;
    v.z = az * inv + sk.z;
    v.w = aw * inv + sk.w;
    v.x = v.x > 0.f ? v.x : expm1f(v.x);
    v.y = v.y > 0.f ? v.y : expm1f(v.y);
    v.z = v.z > 0.f ? v.z : expm1f(v.z);
    v.w = v.w > 0.f ? v.w : expm1f(v.w);
    *(float4*)&out[(size_t)node * HF + lane * 4] = v;
}

extern "C" void kernel_launch(void* const* d_in, const int* in_sizes, int n_in,
                              void* d_out, int out_size, void* d_ws, size_t ws_size,
                              hipStream_t stream) {
    const float* x     = (const float*)d_in[0];
    const int*   ei    = (const int*)d_in[1];
    const float* Wp    = (const float*)d_in[2];
    const float* a_src = (const float*)d_in[3];
    const float* a_trg = (const float*)d_in[4];
    const float* Wskip = (const float*)d_in[5];
    const float* bias  = (const float*)d_in[6];
    float* out = (float*)d_out;

    const int N = in_sizes[0] / FIN;
    const int E = in_sizes[1] / 2;
    const int nsb = (N + 4095) / 4096;

    // workspace layout
    unsigned short* projb = (unsigned short*)d_ws;               // N*HF bf16
    float* ssrc          = (float*)(projb + (size_t)N * HF);     // N*NH
    float* strg          = ssrc + (size_t)N * NH;                // N*NH
    unsigned short* A2   = (unsigned short*)(strg + (size_t)N * NH);  // N*512
    unsigned short* W2   = A2 + (size_t)N * 512;                 // 512*512
    int* deg             = (int*)(W2 + 512 * 512);               // N
    int* rp              = deg + N;                              // N+1
    int* cursor          = rp + (N + 1);                         // N
    int* bsum            = cursor + N;                           // 16
    int* col             = bsum + 16;                            // E

    hipMemsetAsync(deg, 0, (size_t)N * sizeof(int), stream);

    convert_k<<<(N + 512 + 3) / 4, 256, 0, stream>>>(x, Wp, Wskip, A2, W2, N);

    dim3 ggrid((N + 127) / 128, 4);
    mfma_gemm<<<ggrid, 256, 0, stream>>>(A2, W2, bias, a_src, a_trg,
                                         projb, ssrc, strg, out, N);

    hist_k<<<1024, 256, 0, stream>>>(ei, deg, E);

    scan1_k<<<nsb, 256, 0, stream>>>(deg, rp, bsum, N);
    scan2_k<<<1, 64, 0, stream>>>(bsum, nsb);
    scan3_k<<<(N + 255) / 256, 256, 0, stream>>>(rp, bsum, cursor, N, E);

    scatter_k<<<1024, 256, 0, stream>>>(ei, cursor, col, E);

    gather_k<<<(N + 3) / 4, 256, 0, stream>>>(rp, col, ssrc, strg, projb, out, N);
}